// Round 3
// baseline (317.547 us; speedup 1.0000x reference)
//
#include <hip/hip_runtime.h>
#include <hip/hip_bf16.h>

// BinaryMoSLinear: B=4, S=2048 -> N=8192 rows; H=O=4096; E=4.
#define H_DIM 4096
#define O_DIM 4096
#define N_ROWS 8192

typedef __bf16 bf16x8 __attribute__((ext_vector_type(8)));
typedef float  f32x4  __attribute__((ext_vector_type(4)));

__device__ __forceinline__ unsigned short f32_bf16_rne(float f) {
    unsigned int u = __builtin_bit_cast(unsigned int, f);
    u += 0x7FFFu + ((u >> 16) & 1u);
    return (unsigned short)(u >> 16);
}

__device__ __forceinline__ void gload_lds16(const unsigned short* g, unsigned short* l) {
    __builtin_amdgcn_global_load_lds((const __attribute__((address_space(1))) void*)g,
                                     (__attribute__((address_space(3))) void*)l,
                                     16, 0, 0);
}

// ---------------------------------------------------------------------------
// Kernel 1: bw = sign(weight) as bf16 (+1.0 / -1.0 / 0.0).
// ---------------------------------------------------------------------------
__global__ void __launch_bounds__(256) sign_kernel(const float* __restrict__ w,
                                                   unsigned short* __restrict__ bw) {
    size_t i = ((size_t)blockIdx.x * 256 + threadIdx.x) * 4;
    float4 v = *reinterpret_cast<const float4*>(w + i);
    ushort4 o;
    o.x = v.x > 0.f ? 0x3F80 : (v.x < 0.f ? 0xBF80 : 0);
    o.y = v.y > 0.f ? 0x3F80 : (v.y < 0.f ? 0xBF80 : 0);
    o.z = v.z > 0.f ? 0x3F80 : (v.z < 0.f ? 0xBF80 : 0);
    o.w = v.w > 0.f ? 0x3F80 : (v.w < 0.f ? 0xBF80 : 0);
    *reinterpret_cast<ushort4*>(bw + i) = o;
}

// ---------------------------------------------------------------------------
// Kernel 2: router softmax -> rw[n][4]; xs = bf16(x * (rw @ in_channel_scale)).
// ---------------------------------------------------------------------------
__global__ void __launch_bounds__(256) route_scale_kernel(
    const float* __restrict__ x, const float* __restrict__ gate_w,
    const float* __restrict__ ics, float* __restrict__ rw_out,
    unsigned short* __restrict__ xs_out)
{
    __shared__ float red[4][4];
    const int n = blockIdx.x;
    const int t = threadIdx.x;
    const float* xr = x + (size_t)n * H_DIM;

    float4 xv[4];
    float lg[4] = {0.f, 0.f, 0.f, 0.f};
#pragma unroll
    for (int c = 0; c < 4; ++c) {
        const int idx = c * 1024 + t * 4;
        xv[c] = *reinterpret_cast<const float4*>(xr + idx);
#pragma unroll
        for (int e = 0; e < 4; ++e) {
            float4 g = *reinterpret_cast<const float4*>(gate_w + e * H_DIM + idx);
            lg[e] += xv[c].x * g.x + xv[c].y * g.y + xv[c].z * g.z + xv[c].w * g.w;
        }
    }
#pragma unroll
    for (int e = 0; e < 4; ++e) {
#pragma unroll
        for (int off = 1; off < 64; off <<= 1)
            lg[e] += __shfl_xor(lg[e], off, 64);
    }
    if ((t & 63) == 0) {
        const int w = t >> 6;
        red[w][0] = lg[0]; red[w][1] = lg[1]; red[w][2] = lg[2]; red[w][3] = lg[3];
    }
    __syncthreads();
    const float l0 = red[0][0] + red[1][0] + red[2][0] + red[3][0];
    const float l1 = red[0][1] + red[1][1] + red[2][1] + red[3][1];
    const float l2 = red[0][2] + red[1][2] + red[2][2] + red[3][2];
    const float l3 = red[0][3] + red[1][3] + red[2][3] + red[3][3];
    const float m  = fmaxf(fmaxf(l0, l1), fmaxf(l2, l3));
    const float p0 = expf(l0 - m), p1 = expf(l1 - m), p2 = expf(l2 - m), p3 = expf(l3 - m);
    const float inv = 1.f / (p0 + p1 + p2 + p3);
    const float w0 = p0 * inv, w1 = p1 * inv, w2 = p2 * inv, w3 = p3 * inv;
    if (t == 0) {
        float4 wv = make_float4(w0, w1, w2, w3);
        *reinterpret_cast<float4*>(rw_out + (size_t)n * 4) = wv;
    }
#pragma unroll
    for (int c = 0; c < 4; ++c) {
        const int idx = c * 1024 + t * 4;
        float4 i0 = *reinterpret_cast<const float4*>(ics + 0 * H_DIM + idx);
        float4 i1 = *reinterpret_cast<const float4*>(ics + 1 * H_DIM + idx);
        float4 i2 = *reinterpret_cast<const float4*>(ics + 2 * H_DIM + idx);
        float4 i3 = *reinterpret_cast<const float4*>(ics + 3 * H_DIM + idx);
        const float sx = w0 * i0.x + w1 * i1.x + w2 * i2.x + w3 * i3.x;
        const float sy = w0 * i0.y + w1 * i1.y + w2 * i2.y + w3 * i3.y;
        const float sz = w0 * i0.z + w1 * i1.z + w2 * i2.z + w3 * i3.z;
        const float sw = w0 * i0.w + w1 * i1.w + w2 * i2.w + w3 * i3.w;
        ushort4 o;
        o.x = f32_bf16_rne(xv[c].x * sx);
        o.y = f32_bf16_rne(xv[c].y * sy);
        o.z = f32_bf16_rne(xv[c].z * sz);
        o.w = f32_bf16_rne(xv[c].w * sw);
        *reinterpret_cast<ushort4*>(xs_out + (size_t)n * H_DIM + idx) = o;
    }
}

// ---------------------------------------------------------------------------
// Kernel 3: C = (xs @ bw^T) * (rw @ ocs) + bias  — cross-window pipelined LDS
//
// 256x256 tile, 8 waves (2Mx4N), BK=32, 4-slot LDS ring (128 KiB).
// 128 windows; window W computes K-slice W on regs loaded at W-1 while its
// 12 ds_reads for W+1 are in flight (compiler emits COUNTED lgkmcnt(12)
// before the MFMA cluster, not 0 -> LDS service overlaps MFMA execution).
// sched_barrier(0) walls pin {stage|gate} < {reads} < {MFMA} emission order.
// One s_barrier per window (after MFMA).
//
// Ledger (4 gload calls per tile batch; certification = own-wave counted
// vmcnt + one intervening s_barrier for cross-wave visibility):
//   prologue: stage T0,T1,T2 (12 calls); vmcnt(4) retires T0,T1; barrier;
//             preload regs(T0).
//   window W: stage T(W+3) -> slot (W+3)&3  [slot last read at W-1; all
//               waves' W-1 reads completed before the W-1 end barrier]
//             vmcnt(4): retires all but this window's batch => T(W+2) landed
//               in every wave before the NEXT barrier -> W+1's reads of
//               T(W+2)... and T(W+1) was certified at window W-1 + barrier,
//               so this window's reads of slot (W+1)&3 are safe.
//             12 ds_reads (T(W+1)) -> ping-pong reg set
//             32 MFMA on current set (waits lgkmcnt(12) auto)
//             s_barrier
//   tail: W=124 stages T127 (last); W=125 gate vmcnt(0); W=126/127 no gate;
//         W=127 no reads/barrier.
// Swizzle (R0-proven, conflicts=0): logical (row, 16B-chunk c) at physical
// chunk c ^ ((row>>1)&3); applied on pre-swizzled global source and LDS read.
// LDS map: A slot s @ s*16384 (256 rows x 64 B); B slot s @ 65536 + s*16384.
// ---------------------------------------------------------------------------

#define GATE4 asm volatile("s_waitcnt vmcnt(4)" ::: "memory")
#define GATE0 asm volatile("s_waitcnt vmcnt(0)" ::: "memory")
#define NOGATE

#define WINDOW(W, CA_, CB_, NA_, NB_, DO_STAGE, GATE_STMT, DO_READS, DO_BAR)    \
  {                                                                             \
    const int w_ = (W);                                                         \
    if (DO_STAGE) {                                                             \
      const int ks_ = w_ + 3;                                                   \
      char* sA_ = lds + (ks_ & 3) * 16384;                                      \
      char* sB_ = lds + 65536 + (ks_ & 3) * 16384;                              \
      _Pragma("unroll")                                                         \
      for (int j = 0; j < 2; ++j) {                                             \
        gload_lds16(gA + ((size_t)j * 128) * H_DIM + ks_ * 32,                  \
                    (unsigned short*)(sA_ + j * 8192 + wv * 1024));             \
        gload_lds16(gB + ((size_t)j * 128) * H_DIM + ks_ * 32,                  \
                    (unsigned short*)(sB_ + j * 8192 + wv * 1024));             \
      }                                                                         \
    }                                                                           \
    GATE_STMT;                                                                  \
    __builtin_amdgcn_sched_barrier(0);                                          \
    if (DO_READS) {                                                             \
      const int sb_ = ((w_ + 1) & 3) * 16384;                                   \
      _Pragma("unroll")                                                         \
      for (int fr = 0; fr < 8; ++fr)                                            \
        NA_[fr] = *reinterpret_cast<const bf16x8*>(lds + sb_ + aOff[fr]);       \
      _Pragma("unroll")                                                         \
      for (int ni = 0; ni < 4; ++ni)                                            \
        NB_[ni] = *reinterpret_cast<const bf16x8*>(lds + 65536 + sb_ + bOff[ni]); \
    }                                                                           \
    __builtin_amdgcn_sched_barrier(0);                                          \
    __builtin_amdgcn_s_setprio(1);                                              \
    _Pragma("unroll")                                                           \
    for (int fr = 0; fr < 8; ++fr)                                              \
      _Pragma("unroll")                                                         \
      for (int ni = 0; ni < 4; ++ni)                                            \
        acc[fr][ni] = __builtin_amdgcn_mfma_f32_16x16x32_bf16(CA_[fr], CB_[ni], \
                                                              acc[fr][ni], 0, 0, 0); \
    __builtin_amdgcn_s_setprio(0);                                              \
    __builtin_amdgcn_sched_barrier(0);                                          \
    if (DO_BAR) __builtin_amdgcn_s_barrier();                                   \
  }

__global__ void __launch_bounds__(512, 2) gemm_bin_kernel(
    const unsigned short* __restrict__ xs,   // [N_ROWS][H] bf16
    const unsigned short* __restrict__ bw,   // [O][H] bf16 (row = output col)
    const float* __restrict__ rw,            // [N_ROWS][4]
    const float* __restrict__ ocs,           // [4][O]
    const float* __restrict__ bias,          // [O]
    float* __restrict__ out)                 // [N_ROWS][O]
{
    __shared__ __align__(16) char lds[131072];

    const int t  = threadIdx.x;
    const int wv = t >> 6;
    const int ln = t & 63;
    const int wr = wv >> 2;          // 0..1 -> 128-row half
    const int wc = wv & 3;           // 0..3 -> 64-col quarter

    // T1: bijective XCD swizzle (512 blocks, 512%8==0)
    const int bid = blockIdx.x;
    const int swz = (bid & 7) * 64 + (bid >> 3);
    const int rowBase = (swz >> 4) * 256;    // 32 M-tiles
    const int colBase = (swz & 15) * 256;    // 16 N-tiles

    // staging thread map: row r = j*128 + (t>>2), physical chunk t&3 holds
    // logical chunk (t&3)^((t>>3)&3)  [= (t&3)^((row>>1)&3)]
    const int s_r  = t >> 2;
    const int s_cl = (t & 3) ^ ((t >> 3) & 3);
    const unsigned short* gA = xs + (size_t)(rowBase + s_r) * H_DIM + s_cl * 8;
    const unsigned short* gB = bw + (size_t)(colBase + s_r) * H_DIM + s_cl * 8;

    // read-side fragment byte offsets within a slot (loop-invariant)
    int aOff[8], bOff[4];
#pragma unroll
    for (int fr = 0; fr < 8; ++fr) {
        const int row = wr * 128 + fr * 16 + (ln & 15);
        aOff[fr] = row * 64 + (((ln >> 4) ^ ((row >> 1) & 3)) << 4);
    }
#pragma unroll
    for (int ni = 0; ni < 4; ++ni) {
        const int row = wc * 64 + ni * 16 + (ln & 15);
        bOff[ni] = row * 64 + (((ln >> 4) ^ ((row >> 1) & 3)) << 4);
    }

    f32x4 acc[8][4];
#pragma unroll
    for (int i = 0; i < 8; ++i)
#pragma unroll
        for (int j = 0; j < 4; ++j) acc[i][j] = (f32x4){0.f, 0.f, 0.f, 0.f};

    // ---- prologue: stage tiles 0,1,2 (slots 0,1,2) ----
#pragma unroll
    for (int kt = 0; kt < 3; ++kt) {
        char* sA = lds + kt * 16384;
        char* sB = lds + 65536 + kt * 16384;
#pragma unroll
        for (int j = 0; j < 2; ++j) {
            gload_lds16(gA + ((size_t)j * 128) * H_DIM + kt * 32,
                        (unsigned short*)(sA + j * 8192 + wv * 1024));
            gload_lds16(gB + ((size_t)j * 128) * H_DIM + kt * 32,
                        (unsigned short*)(sB + j * 8192 + wv * 1024));
        }
    }
    GATE4;                               // retires T0,T1 (leaves T2 flying)
    __builtin_amdgcn_s_barrier();        // -> T0,T1 certified block-wide

    // preload current register set from tile 0 (slot 0)
    bf16x8 avA[8], bvA[4], avB[8], bvB[4];
#pragma unroll
    for (int fr = 0; fr < 8; ++fr)
        avA[fr] = *reinterpret_cast<const bf16x8*>(lds + aOff[fr]);
#pragma unroll
    for (int ni = 0; ni < 4; ++ni)
        bvA[ni] = *reinterpret_cast<const bf16x8*>(lds + 65536 + bOff[ni]);

    // ---- main loop: windows 0..123 (steady), 124..127 peeled ----
    for (int w = 0; w < 124; w += 2) {
        WINDOW(w,     avA, bvA, avB, bvB, 1, GATE4, 1, 1);
        WINDOW(w + 1, avB, bvB, avA, bvA, 1, GATE4, 1, 1);
    }
    WINDOW(124, avA, bvA, avB, bvB, 1, GATE4,  1, 1);   // stages T127 (last)
    WINDOW(125, avB, bvB, avA, bvA, 0, GATE0,  1, 1);   // certify T127
    WINDOW(126, avA, bvA, avB, bvB, 0, NOGATE, 1, 1);
    WINDOW(127, avB, bvB, avA, bvA, 0, NOGATE, 0, 0);

    // ---- epilogue: y = acc * (rw . ocs[:,col]) + bias ----
    float oce[4][4], bve[4];
    int cole[4];
#pragma unroll
    for (int ni = 0; ni < 4; ++ni) {
        const int col = colBase + wc * 64 + ni * 16 + (ln & 15);
        cole[ni] = col;
        oce[ni][0] = ocs[0 * O_DIM + col];
        oce[ni][1] = ocs[1 * O_DIM + col];
        oce[ni][2] = ocs[2 * O_DIM + col];
        oce[ni][3] = ocs[3 * O_DIM + col];
        bve[ni] = bias[col];
    }
#pragma unroll
    for (int fr = 0; fr < 8; ++fr) {
        float4 rwv[4];
        int rowe[4];
#pragma unroll
        for (int j = 0; j < 4; ++j) {
            const int row = rowBase + wr * 128 + fr * 16 + (ln >> 4) * 4 + j;
            rowe[j] = row;
            rwv[j] = *reinterpret_cast<const float4*>(rw + (size_t)row * 4);
        }
#pragma unroll
        for (int ni = 0; ni < 4; ++ni) {
#pragma unroll
            for (int j = 0; j < 4; ++j) {
                const float os = rwv[j].x * oce[ni][0] + rwv[j].y * oce[ni][1] +
                                 rwv[j].z * oce[ni][2] + rwv[j].w * oce[ni][3];
                out[(size_t)rowe[j] * O_DIM + cole[ni]] = acc[fr][ni][j] * os + bve[ni];
            }
        }
    }
}

// ---------------------------------------------------------------------------
extern "C" void kernel_launch(void* const* d_in, const int* in_sizes, int n_in,
                              void* d_out, int out_size, void* d_ws, size_t ws_size,
                              hipStream_t stream) {
    const float* x      = (const float*)d_in[0];
    const float* weight = (const float*)d_in[1];
    const float* bias   = (const float*)d_in[2];
    const float* gate_w = (const float*)d_in[3];
    const float* ics    = (const float*)d_in[4];
    const float* ocs    = (const float*)d_in[5];
    float* out = (float*)d_out;

    unsigned short* xs = (unsigned short*)d_ws;                      // [N][H] bf16
    unsigned short* bw = xs + (size_t)N_ROWS * H_DIM;                // [O][H] bf16
    float* rw = (float*)(bw + (size_t)O_DIM * H_DIM);                // [N][4]

    sign_kernel<<<(O_DIM * H_DIM) / (256 * 4), 256, 0, stream>>>(weight, bw);
    route_scale_kernel<<<N_ROWS, 256, 0, stream>>>(x, gate_w, ics, rw, xs);
    gemm_bin_kernel<<<(N_ROWS / 256) * (O_DIM / 256), 512, 0, stream>>>(xs, bw, rw, ocs, bias, out);
}